// Round 9
// baseline (808.251 us; speedup 1.0000x reference)
//
#include <hip/hip_runtime.h>
#include <hip/hip_cooperative_groups.h>
#include <math.h>

namespace cg = cooperative_groups;

#define SEQL  256
#define HDIM  64
#define PADID 49999
#define NEGV  -4294967295.0f
#define LNEPS 1e-8f
#define INV_SQRT_HS 0.17677669529663687f
#define TKC   257
#define TKTLD 260
#define QG    4
#define ROWS  4096
#define NTILE 1024            // work tiles per phase (4 rows each)

struct Params {
    const int *seqs_data, *positions, *tmat;
    const float *seqs, *apK, *apV, *tKtab, *tVtab;
    const float *Qw, *Qb, *Kw, *Kb, *Vw, *Vb, *g1, *b1, *g2, *b2;
    const float *W1, *fb1, *W2, *fb2, *lastg, *lastb;
    float *x, *q_in, *Qo, *Vp, *KpT, *tKtabT, *out;
};

union SmemU {
    struct {                       // attention phase
        float qs[QG][HDIM];
        float Tk[QG][2][TKTLD];
        float A[QG][2][SEQL];
        float Wl[QG][2][TKTLD];
        float outred[4][QG][HDIM];
        float redm[QG][2][4];
        float reds[QG][2][4];
    } a;                           // ~30.2 KB
    struct {                       // prep / ffn / transpose phases
        float t0[64][65];
        float t1[64][65];
        float xs[4][HDIM];
        float qs[4][HDIM];
        float kx[HDIM][5];
    } w;                           // ~36.6 KB
};

__device__ __forceinline__ float waveReduceSum(float v) {
#pragma unroll
    for (int o = 32; o > 0; o >>= 1) v += __shfl_xor(v, o);
    return v;
}

__device__ __forceinline__ int swz(int i) { return ((i & 7) << 7) | (i >> 3); }

__global__ __launch_bounds__(256, 4) void mega_kernel(Params p)
{
    cg::grid_group grid = cg::this_grid();
    __shared__ SmemU sm;
    const int tid = threadIdx.x;
    const int w = tid >> 6, t = tid & 63;

    auto stage = [&](float (*tile)[65], const float* __restrict__ src) {
#pragma unroll
        for (int pp = 0; pp < 16; ++pp)
            tile[pp*4 + w][t] = src[(size_t)(pp*4 + w)*64 + t];
    };

    // Requires sm.w.qs = LN1 output, sm.w.xs = pre-LN x (keep-masked).
    // GEMVs read STAGED-RAW weights as tile[t][mth]  (== W[t][m], i.e. x@W^T).
    auto project_qkv = [&](int blk, int layer) {
        const int row0 = blk << 2;
        const int row = row0 + w;
        int pos = p.positions[row];
        float aKv = pos ? p.apK[(size_t)pos*HDIM + t] : 0.f;
        float aVv = pos ? p.apV[(size_t)pos*HDIM + t] : 0.f;
        stage(sm.w.t0, p.Qw + layer*4096);
        stage(sm.w.t1, p.Kw + layer*4096);
        __syncthreads();
        float aq = 0.f, ak = 0.f;
#pragma unroll 16
        for (int mth = 0; mth < 64; ++mth) {
            aq += sm.w.qs[w][mth] * sm.w.t0[t][mth];
            ak += sm.w.xs[w][mth] * sm.w.t1[t][mth];
        }
        p.Qo[(size_t)row*HDIM + t] = aq + p.Qb[layer*HDIM + t];
        sm.w.kx[t][w] = ak + p.Kb[layer*HDIM + t] + aKv;
        __syncthreads();
        stage(sm.w.t0, p.Vw + layer*4096);
        p.KpT[(size_t)(tid>>2)*ROWS + row0 + (tid&3)] = sm.w.kx[tid>>2][tid&3];
        __syncthreads();
        float av = 0.f;
#pragma unroll 16
        for (int mth = 0; mth < 64; ++mth)
            av += sm.w.xs[w][mth] * sm.w.t0[t][mth];
        p.Vp[(size_t)row*HDIM + t] = av + p.Vb[layer*HDIM + t] + aVv;
    };

    auto prep0 = [&](int blk) {
        __syncthreads();
        const int row = (blk << 2) + w;
        float xv = p.seqs[(size_t)row*HDIM + t];
        if (p.seqs_data[row] == PADID) xv = 0.f;
        float mean = waveReduceSum(xv) * (1.f/HDIM);
        float d = xv - mean;
        float var = waveReduceSum(d*d) * (1.f/HDIM);
        float q = p.g1[t] * d / sqrtf(var + LNEPS) + p.b1[t];
        sm.w.xs[w][t] = xv;
        sm.w.qs[w][t] = q;
        p.q_in[(size_t)row*HDIM + t] = q;
        project_qkv(blk, 0);
    };

    auto attn_phase = [&](int blk) {
        __syncthreads();
        const int ab = blk >> 6, al0 = (blk & 63) << 2;
        const int arow0 = ab * SEQL + al0;
        const int m = tid, lane = t, wv = w;
        for (int k = tid; k < QG*2*TKTLD; k += 256) (&sm.a.Wl[0][0][0])[k] = 0.f;
        sm.a.qs[w][t] = p.Qo[(size_t)(arow0 + w)*HDIM + t];
        bool qpad[QG]; bool anypad = false;
#pragma unroll
        for (int li = 0; li < QG; ++li) {
            qpad[li] = (p.seqs_data[arow0 + li] == PADID);
            anypad |= qpad[li];
        }
        const int lmax = al0 + QG - 1;
        int tmc[QG];
#pragma unroll
        for (int li = 0; li < QG; ++li)
            tmc[li] = p.tmat[(size_t)(arow0 + li)*SEQL + m];
        __syncthreads();
        for (int c = tid; c < TKC; c += 256) {
            float a00=0,a10=0,a20=0,a30=0,a01=0,a11=0,a21=0,a31=0;
#pragma unroll 8
            for (int dd = 0; dd < 32; ++dd) {
                float tt = p.tKtabT[dd*TKTLD + c];
                a00 += tt*sm.a.qs[0][dd]; a10 += tt*sm.a.qs[1][dd];
                a20 += tt*sm.a.qs[2][dd]; a30 += tt*sm.a.qs[3][dd];
            }
#pragma unroll 8
            for (int dd = 32; dd < 64; ++dd) {
                float tt = p.tKtabT[dd*TKTLD + c];
                a01 += tt*sm.a.qs[0][dd]; a11 += tt*sm.a.qs[1][dd];
                a21 += tt*sm.a.qs[2][dd]; a31 += tt*sm.a.qs[3][dd];
            }
            sm.a.Tk[0][0][c]=a00; sm.a.Tk[1][0][c]=a10; sm.a.Tk[2][0][c]=a20; sm.a.Tk[3][0][c]=a30;
            sm.a.Tk[0][1][c]=a01; sm.a.Tk[1][1][c]=a11; sm.a.Tk[2][1][c]=a21; sm.a.Tk[3][1][c]=a31;
        }
        __syncthreads();
        float p0v[QG], p1v[QG];
        const bool waveAllMasked = (wv*64 > lmax) && !anypad;
        if (waveAllMasked) {
#pragma unroll
            for (int li = 0; li < QG; ++li) { p0v[li] = NEGV; p1v[li] = NEGV; }
        } else {
            float s0[QG] = {0,0,0,0}, s1[QG] = {0,0,0,0};
            const float* kpb = p.KpT + (size_t)ab*SEQL + m;
#pragma unroll 8
            for (int dd = 0; dd < 32; ++dd) {
                float kv0 = kpb[(size_t)dd*ROWS];
                float kv1 = kpb[(size_t)(dd+32)*ROWS];
#pragma unroll
                for (int li = 0; li < QG; ++li) {
                    s0[li] += kv0 * sm.a.qs[li][dd];
                    s1[li] += kv1 * sm.a.qs[li][dd+32];
                }
            }
#pragma unroll
            for (int li = 0; li < QG; ++li) {
                float v0 = (s0[li] + sm.a.Tk[li][0][tmc[li]]) * INV_SQRT_HS;
                float v1 = (s1[li] + sm.a.Tk[li][1][tmc[li]]) * INV_SQRT_HS;
                bool masked = (m > al0 + li) || qpad[li];
                p0v[li] = masked ? NEGV : v0;
                p1v[li] = masked ? NEGV : v1;
            }
        }
#pragma unroll
        for (int li = 0; li < QG; ++li) {
            float a0 = p0v[li], a1 = p1v[li];
#pragma unroll
            for (int o = 32; o > 0; o >>= 1) {
                a0 = fmaxf(a0, __shfl_xor(a0, o));
                a1 = fmaxf(a1, __shfl_xor(a1, o));
            }
            if (lane == 0) { sm.a.redm[li][0][wv] = a0; sm.a.redm[li][1][wv] = a1; }
        }
        __syncthreads();
#pragma unroll
        for (int li = 0; li < QG; ++li) {
            float m0 = fmaxf(fmaxf(sm.a.redm[li][0][0], sm.a.redm[li][0][1]),
                             fmaxf(sm.a.redm[li][0][2], sm.a.redm[li][0][3]));
            float m1 = fmaxf(fmaxf(sm.a.redm[li][1][0], sm.a.redm[li][1][1]),
                             fmaxf(sm.a.redm[li][1][2], sm.a.redm[li][1][3]));
            float e0 = __expf(p0v[li] - m0), e1 = __expf(p1v[li] - m1);
            p0v[li] = e0; p1v[li] = e1;
            float ts0 = waveReduceSum(e0), ts1 = waveReduceSum(e1);
            if (lane == 0) { sm.a.reds[li][0][wv] = ts0; sm.a.reds[li][1][wv] = ts1; }
        }
        __syncthreads();
#pragma unroll
        for (int li = 0; li < QG; ++li) {
            float sum0 = sm.a.reds[li][0][0] + sm.a.reds[li][0][1] + sm.a.reds[li][0][2] + sm.a.reds[li][0][3];
            float sum1 = sm.a.reds[li][1][0] + sm.a.reds[li][1][1] + sm.a.reds[li][1][2] + sm.a.reds[li][1][3];
            float a0 = p0v[li] / sum0, a1 = p1v[li] / sum1;
            sm.a.A[li][0][m] = a0; sm.a.A[li][1][m] = a1;
            if (a0 != 0.f) atomicAdd(&sm.a.Wl[li][0][tmc[li]], a0);
            if (a1 != 0.f) atomicAdd(&sm.a.Wl[li][1][tmc[li]], a1);
        }
        __syncthreads();
        const int hd = lane, chunk = wv, hh = hd >> 5;
        float acc0 = 0.f, acc1 = 0.f, acc2 = 0.f, acc3 = 0.f;
        const int mend = anypad ? SEQL : (lmax + 1 < SEQL ? lmax + 1 : SEQL);
        const float* vpb = p.Vp + (size_t)(ab*SEQL)*HDIM + hd;
        int mm = chunk;
        for (; mm + 12 < mend; mm += 16) {
            float v0 = vpb[(size_t)(mm)    * HDIM];
            float v1 = vpb[(size_t)(mm+4)  * HDIM];
            float v2 = vpb[(size_t)(mm+8)  * HDIM];
            float v3 = vpb[(size_t)(mm+12) * HDIM];
            acc0 += sm.a.A[0][hh][mm]*v0 + sm.a.A[0][hh][mm+4]*v1 + sm.a.A[0][hh][mm+8]*v2 + sm.a.A[0][hh][mm+12]*v3;
            acc1 += sm.a.A[1][hh][mm]*v0 + sm.a.A[1][hh][mm+4]*v1 + sm.a.A[1][hh][mm+8]*v2 + sm.a.A[1][hh][mm+12]*v3;
            acc2 += sm.a.A[2][hh][mm]*v0 + sm.a.A[2][hh][mm+4]*v1 + sm.a.A[2][hh][mm+8]*v2 + sm.a.A[2][hh][mm+12]*v3;
            acc3 += sm.a.A[3][hh][mm]*v0 + sm.a.A[3][hh][mm+4]*v1 + sm.a.A[3][hh][mm+8]*v2 + sm.a.A[3][hh][mm+12]*v3;
        }
        for (; mm < mend; mm += 4) {
            float vp = vpb[(size_t)mm * HDIM];
            acc0 += sm.a.A[0][hh][mm]*vp; acc1 += sm.a.A[1][hh][mm]*vp;
            acc2 += sm.a.A[2][hh][mm]*vp; acc3 += sm.a.A[3][hh][mm]*vp;
        }
        const float* tvb = p.tVtab + hd;
        int c = chunk;
        for (; c + 12 < TKC; c += 16) {
            float t0 = tvb[(size_t)(c)    * HDIM];
            float t1 = tvb[(size_t)(c+4)  * HDIM];
            float t2 = tvb[(size_t)(c+8)  * HDIM];
            float t3 = tvb[(size_t)(c+12) * HDIM];
            acc0 += sm.a.Wl[0][hh][c]*t0 + sm.a.Wl[0][hh][c+4]*t1 + sm.a.Wl[0][hh][c+8]*t2 + sm.a.Wl[0][hh][c+12]*t3;
            acc1 += sm.a.Wl[1][hh][c]*t0 + sm.a.Wl[1][hh][c+4]*t1 + sm.a.Wl[1][hh][c+8]*t2 + sm.a.Wl[1][hh][c+12]*t3;
            acc2 += sm.a.Wl[2][hh][c]*t0 + sm.a.Wl[2][hh][c+4]*t1 + sm.a.Wl[2][hh][c+8]*t2 + sm.a.Wl[2][hh][c+12]*t3;
            acc3 += sm.a.Wl[3][hh][c]*t0 + sm.a.Wl[3][hh][c+4]*t1 + sm.a.Wl[3][hh][c+8]*t2 + sm.a.Wl[3][hh][c+12]*t3;
        }
        for (; c < TKC; c += 4) {
            float tv = tvb[(size_t)c * HDIM];
            acc0 += sm.a.Wl[0][hh][c]*tv; acc1 += sm.a.Wl[1][hh][c]*tv;
            acc2 += sm.a.Wl[2][hh][c]*tv; acc3 += sm.a.Wl[3][hh][c]*tv;
        }
        sm.a.outred[chunk][0][hd] = acc0;
        sm.a.outred[chunk][1][hd] = acc1;
        sm.a.outred[chunk][2][hd] = acc2;
        sm.a.outred[chunk][3][hd] = acc3;
        __syncthreads();
        {
            const int li = w, dcol = t;
            const int row = arow0 + li;
            float o = sm.a.outred[0][li][dcol] + sm.a.outred[1][li][dcol]
                    + sm.a.outred[2][li][dcol] + sm.a.outred[3][li][dcol];
            p.x[(size_t)row*HDIM + dcol] = p.q_in[(size_t)row*HDIM + dcol] + o;
        }
    };

    auto ffn_prep = [&](int blk, int L) {
        __syncthreads();
        const int row = (blk << 2) + w;
        float xv = p.x[(size_t)row*HDIM + t];
        float mean = waveReduceSum(xv) * (1.f/HDIM);
        float d = xv - mean;
        float var = waveReduceSum(d*d) * (1.f/HDIM);
        float s = p.g2[L*HDIM+t] * d / sqrtf(var + LNEPS) + p.b2[L*HDIM+t];
        sm.w.xs[w][t] = s;
        stage(sm.w.t0, p.W1 + L*4096);
        stage(sm.w.t1, p.W2 + L*4096);
        __syncthreads();
        float ha = 0.f;
#pragma unroll 16
        for (int mth = 0; mth < 64; ++mth) ha += sm.w.xs[w][mth] * sm.w.t0[t][mth];
        float hv = fmaxf(ha + p.fb1[L*HDIM+t], 0.f);
        sm.w.qs[w][t] = hv;                       // same-wave write/read
        float ya = 0.f;
#pragma unroll 16
        for (int mth = 0; mth < 64; ++mth) ya += sm.w.qs[w][mth] * sm.w.t1[t][mth];
        float y = ya + p.fb2[L*HDIM+t] + s;
        if (p.seqs_data[row] == PADID) y = 0.f;
        float mean2 = waveReduceSum(y) * (1.f/HDIM);
        float d2 = y - mean2;
        float var2 = waveReduceSum(d2*d2) * (1.f/HDIM);
        float q = p.g1[(L+1)*HDIM+t] * d2 / sqrtf(var2 + LNEPS) + p.b1[(L+1)*HDIM+t];
        __syncthreads();                          // t0/t1 reads done before restage
        sm.w.xs[w][t] = y;
        sm.w.qs[w][t] = q;
        p.q_in[(size_t)row*HDIM+t] = q;
        project_qkv(blk, L+1);
    };

    auto ffn_final = [&](int blk, int L) {
        __syncthreads();
        const int row = (blk << 2) + w;
        float xv = p.x[(size_t)row*HDIM + t];
        float mean = waveReduceSum(xv) * (1.f/HDIM);
        float d = xv - mean;
        float var = waveReduceSum(d*d) * (1.f/HDIM);
        float s = p.g2[L*HDIM+t] * d / sqrtf(var + LNEPS) + p.b2[L*HDIM+t];
        sm.w.xs[w][t] = s;
        stage(sm.w.t0, p.W1 + L*4096);
        stage(sm.w.t1, p.W2 + L*4096);
        __syncthreads();
        float ha = 0.f;
#pragma unroll 16
        for (int mth = 0; mth < 64; ++mth) ha += sm.w.xs[w][mth] * sm.w.t0[t][mth];
        float hv = fmaxf(ha + p.fb1[L*HDIM+t], 0.f);
        sm.w.qs[w][t] = hv;
        float ya = 0.f;
#pragma unroll 16
        for (int mth = 0; mth < 64; ++mth) ya += sm.w.qs[w][mth] * sm.w.t1[t][mth];
        float y = ya + p.fb2[L*HDIM+t] + s;
        if (p.seqs_data[row] == PADID) y = 0.f;
        float m2 = waveReduceSum(y) * (1.f/HDIM);
        float dd = y - m2;
        float v2 = waveReduceSum(dd*dd) * (1.f/HDIM);
        p.out[(size_t)row*HDIM + t] = p.lastg[t] * dd / sqrtf(v2 + LNEPS) + p.lastb[t];
    };

    // ---- Phase S: transpose tKtab (257x64) -> tKtabT (64x260) ----
    for (int s = blockIdx.x; s < 5; s += gridDim.x) {
        __syncthreads();
        const int s0r = s * 64;
        const int nrows = (s == 4) ? 1 : 64;
#pragma unroll
        for (int pp = 0; pp < 16; ++pp) {
            int r = pp*4 + w;
            if (r < nrows) sm.w.t0[r][t] = p.tKtab[(size_t)(s0r + r)*64 + t];
        }
        __syncthreads();
#pragma unroll
        for (int pp = 0; pp < 16; ++pp) {
            int dd = pp*4 + w;
            if (t < nrows) p.tKtabT[dd*TKTLD + s0r + t] = sm.w.t0[t][dd];
        }
    }
    for (int i = blockIdx.x; i < NTILE; i += gridDim.x) prep0(swz(i));
    __threadfence(); grid.sync();
    for (int i = blockIdx.x; i < NTILE; i += gridDim.x) attn_phase(swz(i));
    __threadfence(); grid.sync();
    for (int i = blockIdx.x; i < NTILE; i += gridDim.x) ffn_prep(swz(i), 0);
    __threadfence(); grid.sync();
    for (int i = blockIdx.x; i < NTILE; i += gridDim.x) attn_phase(swz(i));
    __threadfence(); grid.sync();
    for (int i = blockIdx.x; i < NTILE; i += gridDim.x) ffn_final(swz(i), 1);
}

extern "C" void kernel_launch(void* const* d_in, const int* in_sizes, int n_in,
                              void* d_out, int out_size, void* d_ws, size_t ws_size,
                              hipStream_t stream) {
    const size_t N = (size_t)ROWS * HDIM;   // 262144
    float* ws = (float*)d_ws;

    Params P;
    P.seqs_data = (const int*)d_in[0];
    P.seqs      = (const float*)d_in[1];
    P.positions = (const int*)d_in[2];
    P.tmat      = (const int*)d_in[3];
    P.apK       = (const float*)d_in[4];
    P.apV       = (const float*)d_in[5];
    P.tKtab     = (const float*)d_in[6];
    P.tVtab     = (const float*)d_in[7];
    P.Qw = (const float*)d_in[8];   P.Qb = (const float*)d_in[9];
    P.Kw = (const float*)d_in[10];  P.Kb = (const float*)d_in[11];
    P.Vw = (const float*)d_in[12];  P.Vb = (const float*)d_in[13];
    P.g1 = (const float*)d_in[14];  P.b1 = (const float*)d_in[15];
    P.g2 = (const float*)d_in[16];  P.b2 = (const float*)d_in[17];
    P.W1 = (const float*)d_in[18];  P.fb1 = (const float*)d_in[19];
    P.W2 = (const float*)d_in[20];  P.fb2 = (const float*)d_in[21];
    P.lastg = (const float*)d_in[22]; P.lastb = (const float*)d_in[23];
    P.x     = ws;
    P.q_in  = ws + 1*N;
    P.Qo    = ws + 2*N;
    P.Vp    = ws + 3*N;
    P.KpT   = ws + 4*N;
    P.tKtabT= ws + 5*N;          // 64*260 floats
    P.out   = (float*)d_out;

    int maxPerCU = 0;
    hipOccupancyMaxActiveBlocksPerMultiprocessor(
        &maxPerCU, reinterpret_cast<const void*>(mega_kernel), 256, 0);
    if (maxPerCU < 1) maxPerCU = 1;
    int gridSize = 256 * maxPerCU;
    if (gridSize > NTILE) gridSize = NTILE;

    void* kargs[] = { &P };
    hipLaunchCooperativeKernel(reinterpret_cast<void*>(mega_kernel),
                               dim3(gridSize), dim3(256), kargs, 0, stream);
}

// Round 10
// 286.366 us; speedup vs baseline: 2.8224x; 2.8224x over previous
//
#include <hip/hip_runtime.h>
#include <math.h>

#define BATCH 16
#define SEQL  256
#define HDIM  64
#define PADID 49999
#define NEGV  -4294967295.0f
#define LNEPS 1e-8f
#define INV_SQRT_HS 0.17677669529663687f
#define TKC   257
#define TKTLD 260              // padded LD of tKtabT / Tk tiles
#define WGLD  260              // padded LD of Wg rows (16B-aligned float4)
#define ROWS  4096

__device__ __forceinline__ float waveReduceSum(float v) {
#pragma unroll
    for (int o = 32; o > 0; o >>= 1) v += __shfl_xor(v, o);
    return v;
}

// One-shot transposes: 10 64x64 weight matrices + tKtab (257x64 -> 64x260).
__global__ __launch_bounds__(256) void setup_kernel(
    const float* __restrict__ Qw, const float* __restrict__ Kw,
    const float* __restrict__ Vw, const float* __restrict__ W1,
    const float* __restrict__ W2, const float* __restrict__ tKtab,
    float* __restrict__ QwT, float* __restrict__ KwT, float* __restrict__ VwT,
    float* __restrict__ W1T, float* __restrict__ W2T, float* __restrict__ tKtabT)
{
    __shared__ float tile[64][65];
    const int tid = threadIdx.x;
    const int blk = blockIdx.x;
    if (blk < 10) {
        const float* srcs[10] = {Qw, Qw+4096, Kw, Kw+4096, Vw, Vw+4096,
                                 W1, W1+4096, W2, W2+4096};
        float*       dsts[10] = {QwT, QwT+4096, KwT, KwT+4096, VwT, VwT+4096,
                                 W1T, W1T+4096, W2T, W2T+4096};
        const float* s = srcs[blk];
        float*       d = dsts[blk];
        for (int p = 0; p < 16; ++p) {
            int r = p*4 + (tid>>6), c = tid&63;
            tile[r][c] = s[r*64 + c];
        }
        __syncthreads();
        for (int p = 0; p < 16; ++p) {
            int mth = p*4 + (tid>>6), t = tid&63;
            d[mth*64 + t] = tile[t][mth];
        }
    } else {
        const int s0 = (blk - 10) * 64;
        const int nrows = min(64, TKC - s0);
        for (int p = 0; p < 16; ++p) {
            int rr = p*4 + (tid>>6), c = tid&63;
            if (rr < nrows) tile[rr][c] = tKtab[(size_t)(s0+rr)*64 + c];
        }
        __syncthreads();
        for (int p = 0; p < 16; ++p) {
            int dd = p*4 + (tid>>6), cc = tid&63;
            if (cc < nrows) tKtabT[dd*TKTLD + s0 + cc] = tile[cc][dd];
        }
    }
}

// Layer-0 prep: 4 rows/block, LN1 + Q/Kp/Vp projections (transposed weights).
__global__ __launch_bounds__(256) void prep_kernel(
    const float* __restrict__ xin, const int* __restrict__ seqs_data,
    const int* __restrict__ positions,
    const float* __restrict__ QwT, const float* __restrict__ Qb,
    const float* __restrict__ KwT, const float* __restrict__ Kb,
    const float* __restrict__ VwT, const float* __restrict__ Vb,
    const float* __restrict__ g1, const float* __restrict__ b1,
    const float* __restrict__ apK, const float* __restrict__ apV,
    float* __restrict__ q_in, float* __restrict__ Qo,
    float* __restrict__ KpT, float* __restrict__ Vp)
{
    const int w = threadIdx.x >> 6;
    const int t = threadIdx.x & 63;
    const int row0 = blockIdx.x * 4;
    const int row = row0 + w;
    float x = xin[(size_t)row * HDIM + t];
    if (seqs_data[row] == PADID) x = 0.f;

    float mean = waveReduceSum(x) * (1.f / HDIM);
    float d = x - mean;
    float var = waveReduceSum(d * d) * (1.f / HDIM);
    float q = g1[t] * d / sqrtf(var + LNEPS) + b1[t];

    __shared__ float xs[4][HDIM];
    __shared__ float qs[4][HDIM];
    __shared__ float kx[HDIM][5];
    xs[w][t] = x; qs[w][t] = q;            // same-wave write/read
    q_in[(size_t)row * HDIM + t] = q;

    int pos = positions[row];
    float aK = pos ? apK[(size_t)pos * HDIM + t] : 0.f;
    float aV = pos ? apV[(size_t)pos * HDIM + t] : 0.f;

    float aq = 0.f, ak = 0.f, av = 0.f;
#pragma unroll 16
    for (int mth = 0; mth < 64; ++mth) {
        float qm = qs[w][mth], xm = xs[w][mth];
        aq += qm * QwT[mth*64 + t];
        ak += xm * KwT[mth*64 + t];
        av += xm * VwT[mth*64 + t];
    }
    Qo[(size_t)row * HDIM + t] = aq + Qb[t];
    Vp[(size_t)row * HDIM + t] = av + Vb[t] + aV;
    kx[t][w] = ak + Kb[t] + aK;
    __syncthreads();
    const int f = threadIdx.x >> 2, j = threadIdx.x & 3;
    KpT[(size_t)f * ROWS + row0 + j] = kx[f][j];
}

// Scores+softmax: QG=2 queries per 256-thread block, grid 2048 (8 blocks/CU).
// Writes A[row][2][256] and scatters the time-V histogram Wg[row][2][260].
__global__ __launch_bounds__(256) void attn_score_kernel(
    const float* __restrict__ Qo, const float* __restrict__ KpT,
    const float* __restrict__ tKtabT, const int* __restrict__ seqs_data,
    const int* __restrict__ tmat, float* __restrict__ A, float* __restrict__ Wg)
{
    const int hw = blockIdx.x;
    const int blk = ((hw & 7) << 8) | (hw >> 3);   // XCD swizzle, 2048 blocks
    const int b = blk >> 7, l0 = (blk & 127) << 1;
    const int row0 = b * SEQL + l0;
    const int tid = threadIdx.x, m = tid, lane = tid & 63, wv = tid >> 6;

    __shared__ float qs[2][HDIM];
    __shared__ float Tk[2][2][TKTLD];
    __shared__ float redm[2][2][4];
    __shared__ float reds[2][2][4];

    if (tid < 2*HDIM)
        qs[tid >> 6][tid & 63] = Qo[(size_t)(row0 + (tid >> 6))*HDIM + (tid & 63)];
    const bool qpad0 = (seqs_data[row0]     == PADID);
    const bool qpad1 = (seqs_data[row0 + 1] == PADID);
    const int tm0 = tmat[(size_t)row0*SEQL + m];
    const int tm1 = tmat[(size_t)(row0+1)*SEQL + m];
    __syncthreads();

    // Tk tile: Tk[li][h][c] = Q[li,h] . tKtab[c,h]
    for (int c = tid; c < TKC; c += 256) {
        float a00=0.f,a01=0.f,a10=0.f,a11=0.f;
#pragma unroll 8
        for (int dd = 0; dd < 32; ++dd) {
            float tt = tKtabT[dd*TKTLD + c];
            a00 += tt*qs[0][dd]; a10 += tt*qs[1][dd];
        }
#pragma unroll 8
        for (int dd = 32; dd < 64; ++dd) {
            float tt = tKtabT[dd*TKTLD + c];
            a01 += tt*qs[0][dd]; a11 += tt*qs[1][dd];
        }
        Tk[0][0][c]=a00; Tk[0][1][c]=a01; Tk[1][0][c]=a10; Tk[1][1][c]=a11;
    }
    __syncthreads();

    float s00, s01, s10, s11;
    const bool anypad = qpad0 || qpad1;
    const bool waveAllMasked = (wv*64 > l0 + 1) && !anypad;
    if (waveAllMasked) {
        s00 = s01 = s10 = s11 = NEGV;
    } else {
        float t00=0.f,t01=0.f,t10=0.f,t11=0.f;
        const float* kpb = KpT + (size_t)b*SEQL + m;
#pragma unroll 8
        for (int dd = 0; dd < 32; ++dd) {
            float kv = kpb[(size_t)dd*ROWS];
            t00 += kv*qs[0][dd]; t10 += kv*qs[1][dd];
        }
#pragma unroll 8
        for (int dd = 32; dd < 64; ++dd) {
            float kv = kpb[(size_t)dd*ROWS];
            t01 += kv*qs[0][dd]; t11 += kv*qs[1][dd];
        }
        s00 = (t00 + Tk[0][0][tm0]) * INV_SQRT_HS;
        s01 = (t01 + Tk[0][1][tm0]) * INV_SQRT_HS;
        s10 = (t10 + Tk[1][0][tm1]) * INV_SQRT_HS;
        s11 = (t11 + Tk[1][1][tm1]) * INV_SQRT_HS;
        if ((m > l0)     || qpad0) { s00 = NEGV; s01 = NEGV; }
        if ((m > l0 + 1) || qpad1) { s10 = NEGV; s11 = NEGV; }
    }
    // block max over 4 waves
    {
        float a0=s00, a1=s01, a2=s10, a3=s11;
#pragma unroll
        for (int o = 32; o > 0; o >>= 1) {
            a0 = fmaxf(a0, __shfl_xor(a0, o));
            a1 = fmaxf(a1, __shfl_xor(a1, o));
            a2 = fmaxf(a2, __shfl_xor(a2, o));
            a3 = fmaxf(a3, __shfl_xor(a3, o));
        }
        if (lane == 0) {
            redm[0][0][wv]=a0; redm[0][1][wv]=a1; redm[1][0][wv]=a2; redm[1][1][wv]=a3;
        }
    }
    __syncthreads();
    float M00 = fmaxf(fmaxf(redm[0][0][0],redm[0][0][1]), fmaxf(redm[0][0][2],redm[0][0][3]));
    float M01 = fmaxf(fmaxf(redm[0][1][0],redm[0][1][1]), fmaxf(redm[0][1][2],redm[0][1][3]));
    float M10 = fmaxf(fmaxf(redm[1][0][0],redm[1][0][1]), fmaxf(redm[1][0][2],redm[1][0][3]));
    float M11 = fmaxf(fmaxf(redm[1][1][0],redm[1][1][1]), fmaxf(redm[1][1][2],redm[1][1][3]));
    float e00 = __expf(s00 - M00), e01 = __expf(s01 - M01);
    float e10 = __expf(s10 - M10), e11 = __expf(s11 - M11);
    {
        float t0 = waveReduceSum(e00), t1 = waveReduceSum(e01);
        float t2 = waveReduceSum(e10), t3 = waveReduceSum(e11);
        if (lane == 0) {
            reds[0][0][wv]=t0; reds[0][1][wv]=t1; reds[1][0][wv]=t2; reds[1][1][wv]=t3;
        }
    }
    __syncthreads();
    float S00 = reds[0][0][0]+reds[0][0][1]+reds[0][0][2]+reds[0][0][3];
    float S01 = reds[0][1][0]+reds[0][1][1]+reds[0][1][2]+reds[0][1][3];
    float S10 = reds[1][0][0]+reds[1][0][1]+reds[1][0][2]+reds[1][0][3];
    float S11 = reds[1][1][0]+reds[1][1][1]+reds[1][1][2]+reds[1][1][3];
    float r00 = e00/S00, r01 = e01/S01, r10 = e10/S10, r11 = e11/S11;
    A[((size_t)row0*2 + 0)*SEQL + m]     = r00;
    A[((size_t)row0*2 + 1)*SEQL + m]     = r01;
    A[((size_t)(row0+1)*2 + 0)*SEQL + m] = r10;
    A[((size_t)(row0+1)*2 + 1)*SEQL + m] = r11;
    if (r00 != 0.f) atomicAdd(&Wg[((size_t)row0*2 + 0)*WGLD + tm0], r00);
    if (r01 != 0.f) atomicAdd(&Wg[((size_t)row0*2 + 1)*WGLD + tm0], r01);
    if (r10 != 0.f) atomicAdd(&Wg[((size_t)(row0+1)*2 + 0)*WGLD + tm1], r10);
    if (r11 != 0.f) atomicAdd(&Wg[((size_t)(row0+1)*2 + 1)*WGLD + tm1], r11);
}

// Output: zero-LDS dense reduction out = A@Vp + Wg@tVtab, + residual.
// Thread (w=row-in-tile, t=hd); A/Wg via float4, Vp/tVtab rows coalesced.
__global__ __launch_bounds__(256) void attn_out_kernel(
    const float* __restrict__ A, const float* __restrict__ Wg,
    const float* __restrict__ Vp, const float* __restrict__ tVtab,
    const float* __restrict__ q_in, const int* __restrict__ seqs_data,
    float* __restrict__ x2)
{
    const int hw = blockIdx.x;
    const int blk = ((hw & 7) << 7) | (hw >> 3);   // XCD swizzle, 1024 blocks
    const int row = (blk << 2) + (threadIdx.x >> 6);
    const int t = threadIdx.x & 63;
    const int h = t >> 5;
    const int b = row >> 8, l = row & 255;
    const bool qpad = (seqs_data[row] == PADID);
    const int mend = qpad ? SEQL : l + 1;

    const float4* arow4 = (const float4*)(A + ((size_t)row*2 + h)*SEQL);
    const float*  arow  = (const float*)arow4;
    const float*  vpb   = Vp + (size_t)(b*SEQL)*HDIM + t;
    float acc = 0.f;
    int mm = 0;
    for (; mm + 3 < mend; mm += 4) {
        float4 a4 = arow4[mm >> 2];
        float v0 = vpb[(size_t)(mm)  *HDIM];
        float v1 = vpb[(size_t)(mm+1)*HDIM];
        float v2 = vpb[(size_t)(mm+2)*HDIM];
        float v3 = vpb[(size_t)(mm+3)*HDIM];
        acc += a4.x*v0 + a4.y*v1 + a4.z*v2 + a4.w*v3;
    }
    for (; mm < mend; ++mm) acc += arow[mm] * vpb[(size_t)mm*HDIM];

    const float4* wrow4 = (const float4*)(Wg + ((size_t)row*2 + h)*WGLD);
    const float*  tvb   = tVtab + t;
#pragma unroll 4
    for (int c = 0; c < 256; c += 4) {
        float4 w4 = wrow4[c >> 2];
        acc += w4.x*tvb[(size_t)(c)  *HDIM] + w4.y*tvb[(size_t)(c+1)*HDIM]
             + w4.z*tvb[(size_t)(c+2)*HDIM] + w4.w*tvb[(size_t)(c+3)*HDIM];
    }
    acc += ((const float*)wrow4)[256] * tvb[(size_t)256*HDIM];

    x2[(size_t)row*HDIM + t] = q_in[(size_t)row*HDIM + t] + acc;
}

// Fused: LN2 + FFN + residual + keep (layer i)  ->  LN1 + QKV prep (layer i+1).
__global__ __launch_bounds__(256) void ffnprep_kernel(
    const float* __restrict__ x2, const int* __restrict__ seqs_data,
    const int* __restrict__ positions,
    const float* __restrict__ g2, const float* __restrict__ bg2,
    const float* __restrict__ W1T, const float* __restrict__ bb1,
    const float* __restrict__ W2T, const float* __restrict__ bb2,
    const float* __restrict__ g1n, const float* __restrict__ b1n,
    const float* __restrict__ QwT, const float* __restrict__ Qb,
    const float* __restrict__ KwT, const float* __restrict__ Kb,
    const float* __restrict__ VwT, const float* __restrict__ Vb,
    const float* __restrict__ apK, const float* __restrict__ apV,
    float* __restrict__ q_in, float* __restrict__ Qo,
    float* __restrict__ KpT, float* __restrict__ Vp)
{
    const int w = threadIdx.x >> 6;
    const int t = threadIdx.x & 63;
    const int row0 = blockIdx.x * 4;
    const int row = row0 + w;
    float x = x2[(size_t)row * HDIM + t];
    float mean = waveReduceSum(x) * (1.f / HDIM);
    float d = x - mean;
    float var = waveReduceSum(d * d) * (1.f / HDIM);
    float s = g2[t] * d / sqrtf(var + LNEPS) + bg2[t];

    __shared__ float ss[4][HDIM];
    __shared__ float hs[4][HDIM];
    __shared__ float kx[HDIM][5];
    ss[w][t] = s;
    float acc = 0.f;
#pragma unroll 16
    for (int mth = 0; mth < 64; ++mth)
        acc += ss[w][mth] * W1T[mth*64 + t];
    float hval = fmaxf(acc + bb1[t], 0.f);
    hs[w][t] = hval;
    float acc2 = 0.f;
#pragma unroll 16
    for (int mth = 0; mth < 64; ++mth)
        acc2 += hs[w][mth] * W2T[mth*64 + t];
    float y = acc2 + bb2[t] + s;
    if (seqs_data[row] == PADID) y = 0.f;

    float mean2 = waveReduceSum(y) * (1.f / HDIM);
    float d2 = y - mean2;
    float var2 = waveReduceSum(d2 * d2) * (1.f / HDIM);
    float q = g1n[t] * d2 / sqrtf(var2 + LNEPS) + b1n[t];

    ss[w][t] = y;   // reuse as xs
    hs[w][t] = q;   // reuse as qs
    q_in[(size_t)row * HDIM + t] = q;

    int pos = positions[row];
    float aK = pos ? apK[(size_t)pos * HDIM + t] : 0.f;
    float aV = pos ? apV[(size_t)pos * HDIM + t] : 0.f;

    float aq = 0.f, ak = 0.f, av = 0.f;
#pragma unroll 16
    for (int mth = 0; mth < 64; ++mth) {
        float qm = hs[w][mth], ym = ss[w][mth];
        aq += qm * QwT[mth*64 + t];
        ak += ym * KwT[mth*64 + t];
        av += ym * VwT[mth*64 + t];
    }
    Qo[(size_t)row * HDIM + t] = aq + Qb[t];
    Vp[(size_t)row * HDIM + t] = av + Vb[t] + aV;
    kx[t][w] = ak + Kb[t] + aK;
    __syncthreads();
    const int f = threadIdx.x >> 2, j = threadIdx.x & 3;
    KpT[(size_t)f * ROWS + row0 + j] = kx[f][j];
}

// Final: LN2 + FFN + residual + keep + last LayerNorm -> d_out.
__global__ __launch_bounds__(256) void ffnfinal_kernel(
    const float* __restrict__ x2, const int* __restrict__ seqs_data,
    const float* __restrict__ g2, const float* __restrict__ bg2,
    const float* __restrict__ W1T, const float* __restrict__ bb1,
    const float* __restrict__ W2T, const float* __restrict__ bb2,
    const float* __restrict__ lg, const float* __restrict__ lb,
    float* __restrict__ dout)
{
    const int w = threadIdx.x >> 6;
    const int t = threadIdx.x & 63;
    const int row = blockIdx.x * 4 + w;
    float x = x2[(size_t)row * HDIM + t];
    float mean = waveReduceSum(x) * (1.f / HDIM);
    float d = x - mean;
    float var = waveReduceSum(d * d) * (1.f / HDIM);
    float s = g2[t] * d / sqrtf(var + LNEPS) + bg2[t];

    __shared__ float ss[4][HDIM];
    __shared__ float hs[4][HDIM];
    ss[w][t] = s;
    float acc = 0.f;
#pragma unroll 16
    for (int mth = 0; mth < 64; ++mth)
        acc += ss[w][mth] * W1T[mth*64 + t];
    float hval = fmaxf(acc + bb1[t], 0.f);
    hs[w][t] = hval;
    float acc2 = 0.f;
#pragma unroll 16
    for (int mth = 0; mth < 64; ++mth)
        acc2 += hs[w][mth] * W2T[mth*64 + t];
    float y = acc2 + bb2[t] + s;
    if (seqs_data[row] == PADID) y = 0.f;
    float m2 = waveReduceSum(y) * (1.f / HDIM);
    float dd = y - m2;
    float v2 = waveReduceSum(dd * dd) * (1.f / HDIM);
    dout[(size_t)row * HDIM + t] = lg[t] * dd / sqrtf(v2 + LNEPS) + lb[t];
}

extern "C" void kernel_launch(void* const* d_in, const int* in_sizes, int n_in,
                              void* d_out, int out_size, void* d_ws, size_t ws_size,
                              hipStream_t stream) {
    const int*   seqs_data = (const int*)d_in[0];
    const float* seqs      = (const float*)d_in[1];
    const int*   positions = (const int*)d_in[2];
    const int*   tmat      = (const int*)d_in[3];
    const float* apK       = (const float*)d_in[4];
    const float* apV       = (const float*)d_in[5];
    const float* tKtab     = (const float*)d_in[6];
    const float* tVtab     = (const float*)d_in[7];
    const float* Qw = (const float*)d_in[8];
    const float* Qb = (const float*)d_in[9];
    const float* Kw = (const float*)d_in[10];
    const float* Kb = (const float*)d_in[11];
    const float* Vw = (const float*)d_in[12];
    const float* Vb = (const float*)d_in[13];
    const float* g1 = (const float*)d_in[14];
    const float* b1 = (const float*)d_in[15];
    const float* g2 = (const float*)d_in[16];
    const float* b2 = (const float*)d_in[17];
    const float* W1 = (const float*)d_in[18];
    const float* fb1 = (const float*)d_in[19];
    const float* W2 = (const float*)d_in[20];
    const float* fb2 = (const float*)d_in[21];
    const float* lastg = (const float*)d_in[22];
    const float* lastb = (const float*)d_in[23];

    const size_t N = (size_t)ROWS * HDIM;   // 262144
    float* ws    = (float*)d_ws;
    float* x     = ws;
    float* q_in  = ws + 1 * N;
    float* Qo    = ws + 2 * N;
    float* Vp    = ws + 3 * N;
    float* KpT   = ws + 4 * N;
    float* wtbase = ws + 5 * N;
    float* QwT = wtbase;                 // 2 layers x 4096
    float* KwT = wtbase + 8192;
    float* VwT = wtbase + 16384;
    float* W1T = wtbase + 24576;
    float* W2T = wtbase + 32768;
    float* tKtabT = wtbase + 40960;      // 64*260
    float* A   = wtbase + 40960 + 64*TKTLD;            // 4096*2*256
    float* Wg  = A + (size_t)ROWS * 2 * SEQL;          // 4096*2*260
    const size_t WgBytes = (size_t)ROWS * 2 * WGLD * sizeof(float);

    const int rows = ROWS;

    setup_kernel<<<15, 256, 0, stream>>>(Qw, Kw, Vw, W1, W2, tKtab,
                                         QwT, KwT, VwT, W1T, W2T, tKtabT);

    prep_kernel<<<rows / 4, 256, 0, stream>>>(
        seqs, seqs_data, positions,
        QwT, Qb, KwT, Kb, VwT, Vb, g1, b1,
        apK, apV, q_in, Qo, KpT, Vp);

    hipMemsetAsync(Wg, 0, WgBytes, stream);
    attn_score_kernel<<<rows / 2, 256, 0, stream>>>(
        Qo, KpT, tKtabT, seqs_data, tmat, A, Wg);
    attn_out_kernel<<<rows / 4, 256, 0, stream>>>(
        A, Wg, Vp, tVtab, q_in, seqs_data, x);

    ffnprep_kernel<<<rows / 4, 256, 0, stream>>>(
        x, seqs_data, positions,
        g2, b2, W1T, fb1, W2T, fb2,
        g1 + HDIM, b1 + HDIM,
        QwT + 4096, Qb + HDIM, KwT + 4096, Kb + HDIM, VwT + 4096, Vb + HDIM,
        apK, apV, q_in, Qo, KpT, Vp);

    hipMemsetAsync(Wg, 0, WgBytes, stream);
    attn_score_kernel<<<rows / 2, 256, 0, stream>>>(
        Qo, KpT, tKtabT, seqs_data, tmat, A, Wg);
    attn_out_kernel<<<rows / 4, 256, 0, stream>>>(
        A, Wg, Vp, tVtab, q_in, seqs_data, x);

    ffnfinal_kernel<<<rows / 4, 256, 0, stream>>>(
        x, seqs_data,
        g2 + HDIM, b2 + HDIM, W1T + 4096, fb1 + HDIM, W2T + 4096, fb2 + HDIM,
        lastg, lastb, (float*)d_out);
}

// Round 11
// 213.171 us; speedup vs baseline: 3.7916x; 1.3434x over previous
//
#include <hip/hip_runtime.h>
#include <math.h>

#define SEQL  256
#define HDIM  64
#define PADID 49999
#define NEGV  -4294967295.0f
#define LNEPS 1e-8f
#define INV_SQRT_HS 0.17677669529663687f
#define TKC   257
#define TKTLD 260
#define QG    4
#define ROWS  4096

struct AttnS {
    float qs[QG][HDIM];
    float Tk[QG][2][TKTLD];
    float A[QG][2][SEQL];
    float Wl[QG][2][TKTLD];
    float outred[4][QG][HDIM];
    float redm[QG][2][4];
    float reds[QG][2][4];
};
struct WorkS {
    float t0[64][65];
    float t1[64][65];
    float xs[4][HDIM];
    float qs[4][HDIM];
    float kx[HDIM][5];
};
union SmemU { AttnS a; WorkS w; };

struct FArgs {
    const int *seqs_data, *positions, *tmat;
    const float *apK, *apV, *tVtab, *tKtabT;
    const float *Qo_in, *KpT_in, *Vp_in, *q_in_in;      // layer-L activations
    const float *g2, *b2, *W1, *fb1, *W2, *fb2;         // layer-L FFN (raw weights)
    const float *g1n, *b1n, *Qw, *Qb, *Kw, *Kb, *Vw, *Vb;  // layer-(L+1) prep
    float *q_in_out, *Qo_out, *KpT_out, *Vp_out;
    const float *lastg, *lastb;
    float *out;
    int final_ln;
};

__device__ __forceinline__ float waveReduceSum(float v) {
#pragma unroll
    for (int o = 32; o > 0; o >>= 1) v += __shfl_xor(v, o);
    return v;
}

// K1: LN1 + Q/K/V projections for layer 0 (raw weights staged in LDS),
// plus tKtab transpose in blocks 0..4.
__global__ __launch_bounds__(256, 4) void prep_kernel(
    const float* __restrict__ seqs, const int* __restrict__ seqs_data,
    const int* __restrict__ positions,
    const float* __restrict__ Qw, const float* __restrict__ Qb,
    const float* __restrict__ Kw, const float* __restrict__ Kb,
    const float* __restrict__ Vw, const float* __restrict__ Vb,
    const float* __restrict__ g1, const float* __restrict__ b1,
    const float* __restrict__ apK, const float* __restrict__ apV,
    const float* __restrict__ tKtab, float* __restrict__ tKtabT,
    float* __restrict__ q_in, float* __restrict__ Qo,
    float* __restrict__ KpT, float* __restrict__ Vp)
{
    __shared__ WorkS sw;
    const int tid = threadIdx.x;
    const int hw = blockIdx.x;
    const int blk = ((hw & 7) << 7) | (hw >> 3);   // same swizzle as K2/K3
    const int w = tid >> 6, t = tid & 63;
    const int row0 = blk << 2;
    const int row = row0 + w;

    if (hw < 5) {   // transpose a 64-row slab of tKtab
        const int s0 = hw * 64;
        const int nrows = (hw == 4) ? (TKC - 256) : 64;
#pragma unroll
        for (int pp = 0; pp < 16; ++pp) {
            int r = pp*4 + w;
            if (r < nrows) sw.t0[r][t] = tKtab[(size_t)(s0 + r)*64 + t];
        }
        __syncthreads();
#pragma unroll
        for (int pp = 0; pp < 16; ++pp) {
            int dd = pp*4 + w;
            if (t < nrows) tKtabT[dd*TKTLD + s0 + t] = sw.t0[t][dd];
        }
        __syncthreads();
    }

    float x = seqs[(size_t)row * HDIM + t];
    if (seqs_data[row] == PADID) x = 0.f;
    float mean = waveReduceSum(x) * (1.f / HDIM);
    float d = x - mean;
    float var = waveReduceSum(d * d) * (1.f / HDIM);
    float q = g1[t] * d / sqrtf(var + LNEPS) + b1[t];

    sw.xs[w][t] = x;
    sw.qs[w][t] = q;           // same-wave write/read
    q_in[(size_t)row * HDIM + t] = q;

    int pos = positions[row];
    float aK = pos ? apK[(size_t)pos * HDIM + t] : 0.f;
    float aV = pos ? apV[(size_t)pos * HDIM + t] : 0.f;

#pragma unroll
    for (int pp = 0; pp < 16; ++pp) {
        sw.t0[pp*4 + w][t] = Qw[(size_t)(pp*4 + w)*64 + t];
        sw.t1[pp*4 + w][t] = Kw[(size_t)(pp*4 + w)*64 + t];
    }
    __syncthreads();
    float aq = 0.f, ak = 0.f;
#pragma unroll 16
    for (int mth = 0; mth < 64; ++mth) {
        aq += sw.qs[w][mth] * sw.t0[t][mth];    // W[t][m] -> x@W^T
        ak += sw.xs[w][mth] * sw.t1[t][mth];
    }
    Qo[(size_t)row*HDIM + t] = aq + Qb[t];
    sw.kx[t][w] = ak + Kb[t] + aK;
    __syncthreads();
#pragma unroll
    for (int pp = 0; pp < 16; ++pp)
        sw.t0[pp*4 + w][t] = Vw[(size_t)(pp*4 + w)*64 + t];
    KpT[(size_t)(tid>>2)*ROWS + row0 + (tid&3)] = sw.kx[tid>>2][tid&3];
    __syncthreads();
    float av = 0.f;
#pragma unroll 16
    for (int mth = 0; mth < 64; ++mth)
        av += sw.xs[w][mth] * sw.t0[t][mth];
    Vp[(size_t)row*HDIM + t] = av + Vb[t] + aV;
}

// K2/K3: attention (layer L) fused with LN2+FFN+residual+keep, then either
// next-layer prep (final_ln=0) or the last LayerNorm into d_out (final_ln=1).
__global__ __launch_bounds__(256, 4) void attn_ffn_kernel(FArgs p)
{
    __shared__ SmemU sm;
    __shared__ float x2s[QG][HDIM];
    const int tid = threadIdx.x;
    const int hw = blockIdx.x;
    const int blk = ((hw & 7) << 7) | (hw >> 3);
    const int b = blk >> 6, al0 = (blk & 63) << 2;
    const int row0 = blk << 2;             // == b*SEQL + al0
    const int w = tid >> 6, t = tid & 63;
    const int m = tid, lane = t, wv = w;

    // ---------------- attention ----------------
    for (int k = tid; k < QG*2*TKTLD; k += 256) (&sm.a.Wl[0][0][0])[k] = 0.f;
    sm.a.qs[w][t] = p.Qo_in[(size_t)(row0 + w)*HDIM + t];
    bool qpad[QG]; bool anypad = false;
#pragma unroll
    for (int li = 0; li < QG; ++li) {
        qpad[li] = (p.seqs_data[row0 + li] == PADID);
        anypad |= qpad[li];
    }
    const int lmax = al0 + QG - 1;
    int tmc[QG];
#pragma unroll
    for (int li = 0; li < QG; ++li)
        tmc[li] = p.tmat[(size_t)(row0 + li)*SEQL + m];
    __syncthreads();

    for (int c = tid; c < TKC; c += 256) {
        float a00=0,a10=0,a20=0,a30=0,a01=0,a11=0,a21=0,a31=0;
#pragma unroll 8
        for (int dd = 0; dd < 32; ++dd) {
            float tt = p.tKtabT[dd*TKTLD + c];
            a00 += tt*sm.a.qs[0][dd]; a10 += tt*sm.a.qs[1][dd];
            a20 += tt*sm.a.qs[2][dd]; a30 += tt*sm.a.qs[3][dd];
        }
#pragma unroll 8
        for (int dd = 32; dd < 64; ++dd) {
            float tt = p.tKtabT[dd*TKTLD + c];
            a01 += tt*sm.a.qs[0][dd]; a11 += tt*sm.a.qs[1][dd];
            a21 += tt*sm.a.qs[2][dd]; a31 += tt*sm.a.qs[3][dd];
        }
        sm.a.Tk[0][0][c]=a00; sm.a.Tk[1][0][c]=a10; sm.a.Tk[2][0][c]=a20; sm.a.Tk[3][0][c]=a30;
        sm.a.Tk[0][1][c]=a01; sm.a.Tk[1][1][c]=a11; sm.a.Tk[2][1][c]=a21; sm.a.Tk[3][1][c]=a31;
    }
    __syncthreads();

    float p0v[QG], p1v[QG];
    const bool waveAllMasked = (wv*64 > lmax) && !anypad;
    if (waveAllMasked) {
#pragma unroll
        for (int li = 0; li < QG; ++li) { p0v[li] = NEGV; p1v[li] = NEGV; }
    } else {
        float s0[QG] = {0,0,0,0}, s1[QG] = {0,0,0,0};
        const float* kpb = p.KpT_in + (size_t)b*SEQL + m;
#pragma unroll 8
        for (int dd = 0; dd < 32; ++dd) {
            float kv0 = kpb[(size_t)dd*ROWS];
            float kv1 = kpb[(size_t)(dd+32)*ROWS];
#pragma unroll
            for (int li = 0; li < QG; ++li) {
                s0[li] += kv0 * sm.a.qs[li][dd];
                s1[li] += kv1 * sm.a.qs[li][dd+32];
            }
        }
#pragma unroll
        for (int li = 0; li < QG; ++li) {
            float v0 = (s0[li] + sm.a.Tk[li][0][tmc[li]]) * INV_SQRT_HS;
            float v1 = (s1[li] + sm.a.Tk[li][1][tmc[li]]) * INV_SQRT_HS;
            bool masked = (m > al0 + li) || qpad[li];
            p0v[li] = masked ? NEGV : v0;
            p1v[li] = masked ? NEGV : v1;
        }
    }
#pragma unroll
    for (int li = 0; li < QG; ++li) {
        float a0 = p0v[li], a1 = p1v[li];
#pragma unroll
        for (int o = 32; o > 0; o >>= 1) {
            a0 = fmaxf(a0, __shfl_xor(a0, o));
            a1 = fmaxf(a1, __shfl_xor(a1, o));
        }
        if (lane == 0) { sm.a.redm[li][0][wv] = a0; sm.a.redm[li][1][wv] = a1; }
    }
    __syncthreads();
#pragma unroll
    for (int li = 0; li < QG; ++li) {
        float m0 = fmaxf(fmaxf(sm.a.redm[li][0][0], sm.a.redm[li][0][1]),
                         fmaxf(sm.a.redm[li][0][2], sm.a.redm[li][0][3]));
        float m1 = fmaxf(fmaxf(sm.a.redm[li][1][0], sm.a.redm[li][1][1]),
                         fmaxf(sm.a.redm[li][1][2], sm.a.redm[li][1][3]));
        float e0 = __expf(p0v[li] - m0), e1 = __expf(p1v[li] - m1);
        p0v[li] = e0; p1v[li] = e1;
        float ts0 = waveReduceSum(e0), ts1 = waveReduceSum(e1);
        if (lane == 0) { sm.a.reds[li][0][wv] = ts0; sm.a.reds[li][1][wv] = ts1; }
    }
    __syncthreads();
#pragma unroll
    for (int li = 0; li < QG; ++li) {
        float sum0 = sm.a.reds[li][0][0]+sm.a.reds[li][0][1]+sm.a.reds[li][0][2]+sm.a.reds[li][0][3];
        float sum1 = sm.a.reds[li][1][0]+sm.a.reds[li][1][1]+sm.a.reds[li][1][2]+sm.a.reds[li][1][3];
        float a0 = p0v[li]/sum0, a1 = p1v[li]/sum1;
        sm.a.A[li][0][m] = a0; sm.a.A[li][1][m] = a1;
        if (a0 != 0.f) atomicAdd(&sm.a.Wl[li][0][tmc[li]], a0);
        if (a1 != 0.f) atomicAdd(&sm.a.Wl[li][1][tmc[li]], a1);
    }
    __syncthreads();

    {   // dense pipelined sweeps
        const int hd = lane, chunk = wv, hh = hd >> 5;
        float acc0=0.f, acc1=0.f, acc2=0.f, acc3=0.f;
        const int mend = anypad ? SEQL : (lmax + 1 < SEQL ? lmax + 1 : SEQL);
        const float* vpb = p.Vp_in + (size_t)(b*SEQL)*HDIM + hd;
        int mm = chunk;
        for (; mm + 12 < mend; mm += 16) {
            float v0 = vpb[(size_t)(mm)    * HDIM];
            float v1 = vpb[(size_t)(mm+4)  * HDIM];
            float v2 = vpb[(size_t)(mm+8)  * HDIM];
            float v3 = vpb[(size_t)(mm+12) * HDIM];
            acc0 += sm.a.A[0][hh][mm]*v0 + sm.a.A[0][hh][mm+4]*v1 + sm.a.A[0][hh][mm+8]*v2 + sm.a.A[0][hh][mm+12]*v3;
            acc1 += sm.a.A[1][hh][mm]*v0 + sm.a.A[1][hh][mm+4]*v1 + sm.a.A[1][hh][mm+8]*v2 + sm.a.A[1][hh][mm+12]*v3;
            acc2 += sm.a.A[2][hh][mm]*v0 + sm.a.A[2][hh][mm+4]*v1 + sm.a.A[2][hh][mm+8]*v2 + sm.a.A[2][hh][mm+12]*v3;
            acc3 += sm.a.A[3][hh][mm]*v0 + sm.a.A[3][hh][mm+4]*v1 + sm.a.A[3][hh][mm+8]*v2 + sm.a.A[3][hh][mm+12]*v3;
        }
        for (; mm < mend; mm += 4) {
            float vp = vpb[(size_t)mm * HDIM];
            acc0 += sm.a.A[0][hh][mm]*vp; acc1 += sm.a.A[1][hh][mm]*vp;
            acc2 += sm.a.A[2][hh][mm]*vp; acc3 += sm.a.A[3][hh][mm]*vp;
        }
        const float* tvb = p.tVtab + hd;
        int c = chunk;
        for (; c + 12 < TKC; c += 16) {
            float t0 = tvb[(size_t)(c)    * HDIM];
            float t1 = tvb[(size_t)(c+4)  * HDIM];
            float t2 = tvb[(size_t)(c+8)  * HDIM];
            float t3 = tvb[(size_t)(c+12) * HDIM];
            acc0 += sm.a.Wl[0][hh][c]*t0 + sm.a.Wl[0][hh][c+4]*t1 + sm.a.Wl[0][hh][c+8]*t2 + sm.a.Wl[0][hh][c+12]*t3;
            acc1 += sm.a.Wl[1][hh][c]*t0 + sm.a.Wl[1][hh][c+4]*t1 + sm.a.Wl[1][hh][c+8]*t2 + sm.a.Wl[1][hh][c+12]*t3;
            acc2 += sm.a.Wl[2][hh][c]*t0 + sm.a.Wl[2][hh][c+4]*t1 + sm.a.Wl[2][hh][c+8]*t2 + sm.a.Wl[2][hh][c+12]*t3;
            acc3 += sm.a.Wl[3][hh][c]*t0 + sm.a.Wl[3][hh][c+4]*t1 + sm.a.Wl[3][hh][c+8]*t2 + sm.a.Wl[3][hh][c+12]*t3;
        }
        for (; c < TKC; c += 4) {
            float tv = tvb[(size_t)c * HDIM];
            acc0 += sm.a.Wl[0][hh][c]*tv; acc1 += sm.a.Wl[1][hh][c]*tv;
            acc2 += sm.a.Wl[2][hh][c]*tv; acc3 += sm.a.Wl[3][hh][c]*tv;
        }
        sm.a.outred[chunk][0][hd] = acc0;
        sm.a.outred[chunk][1][hd] = acc1;
        sm.a.outred[chunk][2][hd] = acc2;
        sm.a.outred[chunk][3][hd] = acc3;
    }
    __syncthreads();
    {
        float o = sm.a.outred[0][w][t] + sm.a.outred[1][w][t]
                + sm.a.outred[2][w][t] + sm.a.outred[3][w][t];
        x2s[w][t] = p.q_in_in[(size_t)(row0 + w)*HDIM + t] + o;
    }
    __syncthreads();   // all sm.a reads done; safe to reuse union as sm.w

    // ---------------- LN2 + FFN + residual + keep ----------------
    const int row = row0 + w;
    float xv = x2s[w][t];
    float mean = waveReduceSum(xv) * (1.f/HDIM);
    float d = xv - mean;
    float var = waveReduceSum(d*d) * (1.f/HDIM);
    float s = p.g2[t] * d / sqrtf(var + LNEPS) + p.b2[t];
    sm.w.xs[w][t] = s;
#pragma unroll
    for (int pp = 0; pp < 16; ++pp) {
        sm.w.t0[pp*4 + w][t] = p.W1[(size_t)(pp*4 + w)*64 + t];
        sm.w.t1[pp*4 + w][t] = p.W2[(size_t)(pp*4 + w)*64 + t];
    }
    __syncthreads();
    float ha = 0.f;
#pragma unroll 16
    for (int mth = 0; mth < 64; ++mth) ha += sm.w.xs[w][mth] * sm.w.t0[t][mth];
    float hv = fmaxf(ha + p.fb1[t], 0.f);
    sm.w.qs[w][t] = hv;                      // same-wave write/read
    float ya = 0.f;
#pragma unroll 16
    for (int mth = 0; mth < 64; ++mth) ya += sm.w.qs[w][mth] * sm.w.t1[t][mth];
    float y = ya + p.fb2[t] + s;
    if (p.seqs_data[row] == PADID) y = 0.f;

    if (!p.final_ln) {
        // LN1 of next layer + QKV projection
        float mean2 = waveReduceSum(y) * (1.f/HDIM);
        float d2 = y - mean2;
        float var2 = waveReduceSum(d2*d2) * (1.f/HDIM);
        float q = p.g1n[t] * d2 / sqrtf(var2 + LNEPS) + p.b1n[t];
        __syncthreads();                     // t0/t1 GEMV reads done before restage
        sm.w.xs[w][t] = y;
        sm.w.qs[w][t] = q;
        p.q_in_out[(size_t)row*HDIM + t] = q;

        int pos = p.positions[row];
        float aK = pos ? p.apK[(size_t)pos*HDIM + t] : 0.f;
        float aV = pos ? p.apV[(size_t)pos*HDIM + t] : 0.f;
#pragma unroll
        for (int pp = 0; pp < 16; ++pp) {
            sm.w.t0[pp*4 + w][t] = p.Qw[(size_t)(pp*4 + w)*64 + t];
            sm.w.t1[pp*4 + w][t] = p.Kw[(size_t)(pp*4 + w)*64 + t];
        }
        __syncthreads();
        float aq = 0.f, ak = 0.f;
#pragma unroll 16
        for (int mth = 0; mth < 64; ++mth) {
            aq += sm.w.qs[w][mth] * sm.w.t0[t][mth];
            ak += sm.w.xs[w][mth] * sm.w.t1[t][mth];
        }
        p.Qo_out[(size_t)row*HDIM + t] = aq + p.Qb[t];
        sm.w.kx[t][w] = ak + p.Kb[t] + aK;
        __syncthreads();
#pragma unroll
        for (int pp = 0; pp < 16; ++pp)
            sm.w.t0[pp*4 + w][t] = p.Vw[(size_t)(pp*4 + w)*64 + t];
        p.KpT_out[(size_t)(tid>>2)*ROWS + row0 + (tid&3)] = sm.w.kx[tid>>2][tid&3];
        __syncthreads();
        float av = 0.f;
#pragma unroll 16
        for (int mth = 0; mth < 64; ++mth)
            av += sm.w.xs[w][mth] * sm.w.t0[t][mth];
        p.Vp_out[(size_t)row*HDIM + t] = av + p.Vb[t] + aV;
    } else {
        float m2 = waveReduceSum(y) * (1.f/HDIM);
        float dd = y - m2;
        float v2 = waveReduceSum(dd*dd) * (1.f/HDIM);
        p.out[(size_t)row*HDIM + t] = p.lastg[t] * dd / sqrtf(v2 + LNEPS) + p.lastb[t];
    }
}

extern "C" void kernel_launch(void* const* d_in, const int* in_sizes, int n_in,
                              void* d_out, int out_size, void* d_ws, size_t ws_size,
                              hipStream_t stream) {
    const int*   seqs_data = (const int*)d_in[0];
    const float* seqs      = (const float*)d_in[1];
    const int*   positions = (const int*)d_in[2];
    const int*   tmat      = (const int*)d_in[3];
    const float* apK       = (const float*)d_in[4];
    const float* apV       = (const float*)d_in[5];
    const float* tKtab     = (const float*)d_in[6];
    const float* tVtab     = (const float*)d_in[7];
    const float* Qw = (const float*)d_in[8];
    const float* Qb = (const float*)d_in[9];
    const float* Kw = (const float*)d_in[10];
    const float* Kb = (const float*)d_in[11];
    const float* Vw = (const float*)d_in[12];
    const float* Vb = (const float*)d_in[13];
    const float* g1 = (const float*)d_in[14];
    const float* b1 = (const float*)d_in[15];
    const float* g2 = (const float*)d_in[16];
    const float* b2 = (const float*)d_in[17];
    const float* W1 = (const float*)d_in[18];
    const float* fb1 = (const float*)d_in[19];
    const float* W2 = (const float*)d_in[20];
    const float* fb2 = (const float*)d_in[21];
    const float* lastg = (const float*)d_in[22];
    const float* lastb = (const float*)d_in[23];

    const size_t N = (size_t)ROWS * HDIM;   // 262144
    float* ws = (float*)d_ws;
    float* q_in0 = ws + 0*N;
    float* q_in1 = ws + 1*N;
    float* Qo0   = ws + 2*N;
    float* Qo1   = ws + 3*N;
    float* Vp0   = ws + 4*N;
    float* Vp1   = ws + 5*N;
    float* KpT0  = ws + 6*N;
    float* KpT1  = ws + 7*N;
    float* tKtabT = ws + 8*N;    // 64*260 floats

    prep_kernel<<<1024, 256, 0, stream>>>(
        seqs, seqs_data, positions,
        Qw, Qb, Kw, Kb, Vw, Vb, g1, b1, apK, apV,
        tKtab, tKtabT, q_in0, Qo0, KpT0, Vp0);

    FArgs a0;
    a0.seqs_data = seqs_data; a0.positions = positions; a0.tmat = tmat;
    a0.apK = apK; a0.apV = apV; a0.tVtab = tVtab; a0.tKtabT = tKtabT;
    a0.Qo_in = Qo0; a0.KpT_in = KpT0; a0.Vp_in = Vp0; a0.q_in_in = q_in0;
    a0.g2 = g2; a0.b2 = b2; a0.W1 = W1; a0.fb1 = fb1; a0.W2 = W2; a0.fb2 = fb2;
    a0.g1n = g1 + HDIM; a0.b1n = b1 + HDIM;
    a0.Qw = Qw + 4096; a0.Qb = Qb + HDIM;
    a0.Kw = Kw + 4096; a0.Kb = Kb + HDIM;
    a0.Vw = Vw + 4096; a0.Vb = Vb + HDIM;
    a0.q_in_out = q_in1; a0.Qo_out = Qo1; a0.KpT_out = KpT1; a0.Vp_out = Vp1;
    a0.lastg = lastg; a0.lastb = lastb; a0.out = (float*)d_out;
    a0.final_ln = 0;
    attn_ffn_kernel<<<1024, 256, 0, stream>>>(a0);

    FArgs a1 = a0;
    a1.Qo_in = Qo1; a1.KpT_in = KpT1; a1.Vp_in = Vp1; a1.q_in_in = q_in1;
    a1.g2 = g2 + HDIM; a1.b2 = b2 + HDIM;
    a1.W1 = W1 + 4096; a1.fb1 = fb1 + HDIM;
    a1.W2 = W2 + 4096; a1.fb2 = fb2 + HDIM;
    a1.final_ln = 1;
    attn_ffn_kernel<<<1024, 256, 0, stream>>>(a1);
}